// Round 1
// baseline (12192.835 us; speedup 1.0000x reference)
//
#include <hip/hip_runtime.h>
#include <hip/hip_bf16.h>
#include <math.h>

#define B_ 2
#define S_ 2048
#define F_ 512
#define I_ 1024
#define E_ 8
#define KW_ 7
#define D_ 2
#define CLASSES_ 8192
#define T_ (B_*S_)

#define BM 128
#define BN 128
#define BKK 8
#define LPAD 4

enum AMode { A_PLAIN=0, A_MOE=1, A_CONV=2 };
enum Epi   { EPI_NONE=0, EPI_RELU=1, EPI_FINAL=2 };

// ---------------- embed gather ----------------
__global__ void embed_k(const int* __restrict__ inp, const float* __restrict__ emb,
                        float* __restrict__ X0, float* __restrict__ X1)
{
    int t = blockIdx.x;
    int r = inp[t];
    const float* e = emb + (size_t)r * (2*F_);
    for (int c = threadIdx.x; c < F_; c += 256) {
        X0[(size_t)t*F_ + c] = e[c];
        X1[(size_t)t*F_ + c] = e[F_ + c];
    }
}

// ---------------- gate: G[t][e] = sum_f X[t,f] * GW[f,e] ----------------
__global__ __launch_bounds__(64) void gate_k(const float* __restrict__ X,
                                             const float* __restrict__ GW,
                                             float* __restrict__ G, int W)
{
    __shared__ float xs[1024];
    int t = blockIdx.x;
    const float* xr = X + (size_t)t * W;
    for (int c = threadIdx.x; c < W; c += 64) xs[c] = xr[c];
    __syncthreads();
    int l = threadIdx.x;
    int e = l & 7;
    float p = 0.f;
    for (int f = (l >> 3); f < W; f += 8)
        p += xs[f] * GW[f*E_ + e];
    p += __shfl_xor(p, 8);
    p += __shfl_xor(p, 16);
    p += __shfl_xor(p, 32);
    if (l < 8) G[(size_t)t*E_ + l] = p;
}

// ---------------- top-2 + softmax -> dense combine weights ----------------
__global__ void topk_k(const float* __restrict__ G, float* __restrict__ C)
{
    int t = blockIdx.x * blockDim.x + threadIdx.x;
    if (t >= T_) return;
    float v0 = -3.4e38f, v1 = -3.4e38f; int i0 = 0, i1 = 0;
    #pragma unroll
    for (int e = 0; e < E_; e++) {
        float v = G[(size_t)t*E_ + e];
        if (v > v0)      { v1 = v0; i1 = i0; v0 = v; i0 = e; }
        else if (v > v1) { v1 = v;  i1 = e; }
    }
    float ex = expf(v1 - v0);
    float w0 = 1.f / (1.f + ex);
    float w1 = ex / (1.f + ex);
    #pragma unroll
    for (int e = 0; e < E_; e++)
        C[(size_t)t*E_ + e] = (e == i0) ? w0 : (e == i1) ? w1 : 0.f;
}

// ---------------- conv weight transpose: (o,i,k) -> (k,i,o) ----------------
__global__ void tconv_k(const float* __restrict__ cw, float* __restrict__ Wt)
{
    int g = blockIdx.x * 256 + threadIdx.x;   // over I_*I_
    int o = g & (I_-1), i = g >> 10;
    const float* src = cw + ((size_t)o*I_ + i) * KW_;
    #pragma unroll
    for (int k = 0; k < KW_; k++)
        Wt[((size_t)k*I_ + i) * I_ + o] = src[k];
}

// ---------------- tiled fp32 GEMM, templated A-gen + epilogue ----------------
// C[m][n] = sum_kk A(m,kk) * B(kk,n)
// A_PLAIN: A[m*Kd + kk]
// A_MOE:   A[m*segF + (kk - e*segF)] * comb[m*8+e],  e = kk/segF
// A_CONV:  kk = kc*1024 + i ; A[(m + kc - 6)*segF + i] guarded by s+kc-6>=0
// BT=false: B[kk*N + n] row-major ; BT=true: B[n*Kd + kk]
template<int AM, bool BT, int EP>
__global__ __launch_bounds__(256)
void gemm_k(const float* __restrict__ Ap, const float* __restrict__ Bp,
            float* __restrict__ Cp, int M, int N, int Kd,
            const float* __restrict__ comb, int segF,
            const float* __restrict__ bias)
{
    __shared__ float As[BKK][BM + LPAD];
    __shared__ float Bs[BKK][BN + LPAD];
    int tid = threadIdx.x;
    int m0 = blockIdx.y * BM;
    int n0 = blockIdx.x * BN;
    int ty = tid >> 4, tx = tid & 15;

    int arow = tid >> 1;            // 0..127
    int akc  = (tid & 1) * 4;       // 0 or 4
    int bkk  = tid >> 5;            // 0..7
    int bnc  = (tid & 31) * 4;      // 0..124

    float acc[8][8];
    #pragma unroll
    for (int i = 0; i < 8; i++)
        #pragma unroll
        for (int j = 0; j < 8; j++) acc[i][j] = 0.f;

    for (int k0 = 0; k0 < Kd; k0 += BKK) {
        // ----- A tile -----
        {
            int t = m0 + arow;
            if (AM == A_PLAIN) {
                const float* src = Ap + (size_t)t * Kd + k0 + akc;
                #pragma unroll
                for (int j = 0; j < 4; j++) As[akc + j][arow] = src[j];
            } else if (AM == A_MOE) {
                int e = k0 / segF;                    // uniform in chunk
                int f = k0 - e * segF + akc;
                float cw = comb[(size_t)t*E_ + e];
                const float* src = Ap + (size_t)t * segF + f;
                #pragma unroll
                for (int j = 0; j < 4; j++) As[akc + j][arow] = src[j] * cw;
            } else { // A_CONV
                int kc = k0 >> 10;                    // uniform in chunk
                int i  = (k0 & 1023) + akc;
                int s  = t & (S_ - 1);
                bool ok = (s + kc - 6) >= 0;
                int trow = ok ? (t + kc - 6) : t;     // safe address
                const float* src = Ap + (size_t)trow * segF + i;
                #pragma unroll
                for (int j = 0; j < 4; j++) As[akc + j][arow] = ok ? src[j] : 0.f;
            }
        }
        // ----- B tile -----
        if (!BT) {
            const float* src = Bp + (size_t)(k0 + bkk) * N + n0 + bnc;
            #pragma unroll
            for (int j = 0; j < 4; j++) Bs[bkk][bnc + j] = src[j];
        } else {
            int n = n0 + arow;
            const float* src = Bp + (size_t)n * Kd + k0 + akc;
            #pragma unroll
            for (int j = 0; j < 4; j++) Bs[akc + j][arow] = src[j];
        }
        __syncthreads();
        #pragma unroll
        for (int kk = 0; kk < BKK; kk++) {
            float a[8], b[8];
            #pragma unroll
            for (int i = 0; i < 8; i++) a[i] = As[kk][ty + 16*i];
            #pragma unroll
            for (int j = 0; j < 8; j++) b[j] = Bs[kk][tx + 16*j];
            #pragma unroll
            for (int i = 0; i < 8; i++)
                #pragma unroll
                for (int j = 0; j < 8; j++)
                    acc[i][j] += a[i] * b[j];
        }
        __syncthreads();
    }

    #pragma unroll
    for (int i = 0; i < 8; i++) {
        int m = m0 + ty + 16*i;
        #pragma unroll
        for (int j = 0; j < 8; j++) {
            int n = n0 + tx + 16*j;
            float v = acc[i][j];
            if (EP == EPI_RELU) v = fmaxf(v, 0.f);
            if (EP == EPI_FINAL) {
                v += bias[m];
                int b = n >> 11, s = n & (S_ - 1);
                Cp[((size_t)(b * CLASSES_ + m) << 11) + s] = v;
            } else {
                Cp[(size_t)m * N + n] = v;
            }
        }
    }
}

// ---------------- chunked cumsum over sequence ----------------
#define SC_ 128
#define NCH_ (S_/SC_)
__global__ void cum1(const float* __restrict__ O, float* __restrict__ CS)
{
    int blk = blockIdx.x;               // b*NCH_+ch
    int b = blk / NCH_, ch = blk % NCH_;
    int c = threadIdx.x;                // 512
    int s0 = ch * SC_;
    const float* base = O + ((size_t)(b*S_ + s0)) * (3*F_) + c;
    float sum = 0.f;
    for (int s = 0; s < SC_; s++) sum += base[(size_t)s * (3*F_)];
    CS[(size_t)blk * F_ + c] = sum;
}
__global__ void cum2(float* __restrict__ CS)
{
    int b = blockIdx.x; int c = threadIdx.x;
    float run = 0.f;
    for (int ch = 0; ch < NCH_; ch++) {
        size_t idx = (size_t)(b*NCH_ + ch) * F_ + c;
        float v = CS[idx]; CS[idx] = run; run += v;
    }
}
__global__ void cum3(const float* __restrict__ O, const float* __restrict__ CS,
                     float* __restrict__ FP)
{
    int blk = blockIdx.x;
    int b = blk / NCH_, ch = blk % NCH_;
    int c = threadIdx.x;
    float run = CS[(size_t)blk * F_ + c];
    int s0 = ch * SC_;
    for (int s = s0; s < s0 + SC_; s++) {
        size_t t = (size_t)b * S_ + s;
        const float* row = O + t * (3*F_);
        run += row[c];
        FP[t*F_ + c] = run / (float)(s + 1) * row[F_ + c] + row[2*F_ + c];
    }
}

// ---------------- channel norm (in place on FP rows) ----------------
__global__ __launch_bounds__(256) void norm_k(float* __restrict__ FP)
{
    __shared__ float sb[4];
    int t = blockIdx.x;
    float* row = FP + (size_t)t * F_;
    int tid = threadIdx.x;
    float v0 = row[tid], v1 = row[tid + 256];
    float s = v0 + v1;
    #pragma unroll
    for (int off = 32; off; off >>= 1) s += __shfl_xor(s, off);
    int w = tid >> 6;
    if ((tid & 63) == 0) sb[w] = s;
    __syncthreads();
    float mean = (sb[0] + sb[1] + sb[2] + sb[3]) * (1.0f / F_);
    v0 -= mean; v1 -= mean;
    float q = v0*v0 + v1*v1;
    #pragma unroll
    for (int off = 32; off; off >>= 1) q += __shfl_xor(q, off);
    __syncthreads();
    if ((tid & 63) == 0) sb[w] = q;
    __syncthreads();
    float ss = sb[0] + sb[1] + sb[2] + sb[3];
    float denom = sqrtf(ss) * 0.04419417382415922f + 1e-5f;   // 512^-0.5
    float sc = 0.70710678118654752f / denom;                   // INIT_SCALE
    row[tid] = v0 * sc; row[tid + 256] = v1 * sc;
}

// ---------------- recurrence update ----------------
__global__ void update_k(float* __restrict__ X0, float* __restrict__ X1,
                         const float* __restrict__ FP)
{
    int i = blockIdx.x * 256 + threadIdx.x;
    float a = 0.9f * X0[i] + 0.1f * FP[i];
    X0[i] = a;
    X1[i] = X1[i] + a;
}

// ---------------- concat [X0|X1] ----------------
__global__ void concat_k(const float* __restrict__ X0, const float* __restrict__ X1,
                         float* __restrict__ Xcat)
{
    int t = blockIdx.x;
    for (int c = threadIdx.x; c < F_; c += 256) {
        Xcat[(size_t)t*(2*F_) + c]      = X0[(size_t)t*F_ + c];
        Xcat[(size_t)t*(2*F_) + F_ + c] = X1[(size_t)t*F_ + c];
    }
}

extern "C" void kernel_launch(void* const* d_in, const int* in_sizes, int n_in,
                              void* d_out, int out_size, void* d_ws, size_t ws_size,
                              hipStream_t stream)
{
    const int*   inp    = (const int*)  d_in[0];
    const float* embed  = (const float*)d_in[1];
    const float* gin_w  = (const float*)d_in[2];
    const float* w_in   = (const float*)d_in[3];
    const float* conv_w = (const float*)d_in[4];
    const float* gout_w = (const float*)d_in[5];
    const float* w_out  = (const float*)d_in[6];
    const float* out_w  = (const float*)d_in[7];
    const float* out_b  = (const float*)d_in[8];
    float* out = (float*)d_out;

    float* p = (float*)d_ws;
    float* X0   = p; p += (size_t)T_*F_;
    float* X1   = p; p += (size_t)T_*F_;
    float* Xcat = p; p += (size_t)T_*2*F_;
    float* Cmb  = p; p += (size_t)T_*E_;
    float* G    = p; p += (size_t)T_*E_;
    float* H1   = p; p += (size_t)T_*I_;
    float* HC   = p; p += (size_t)T_*I_;
    float* O    = p; p += (size_t)T_*3*F_;
    float* FP   = p; p += (size_t)T_*F_;
    float* CS   = p; p += (size_t)B_*NCH_*F_;
    float* Wt   = p; p += (size_t)KW_*I_*I_;

    embed_k<<<T_, 256, 0, stream>>>(inp, embed, X0, X1);

    for (int d = 0; d < D_; ++d) {
        tconv_k<<<(I_*I_)/256, 256, 0, stream>>>(conv_w + (size_t)d*I_*I_*KW_, Wt);

        gate_k<<<T_, 64, 0, stream>>>(X1, gin_w + (size_t)d*F_*E_, G, F_);
        topk_k<<<T_/256, 256, 0, stream>>>(G, Cmb);
        gemm_k<A_MOE, false, EPI_RELU><<<dim3(I_/BN, T_/BM), 256, 0, stream>>>(
            X1, w_in + (size_t)d*E_*F_*I_, H1, T_, I_, E_*F_, Cmb, F_, nullptr);

        gemm_k<A_CONV, false, EPI_RELU><<<dim3(I_/BN, T_/BM), 256, 0, stream>>>(
            H1, Wt, HC, T_, I_, KW_*I_, nullptr, I_, nullptr);

        gate_k<<<T_, 64, 0, stream>>>(HC, gout_w + (size_t)d*I_*E_, G, I_);
        topk_k<<<T_/256, 256, 0, stream>>>(G, Cmb);
        gemm_k<A_MOE, false, EPI_NONE><<<dim3((3*F_)/BN, T_/BM), 256, 0, stream>>>(
            HC, w_out + (size_t)d*E_*I_*3*F_, O, T_, 3*F_, E_*I_, Cmb, I_, nullptr);

        cum1<<<B_*NCH_, F_, 0, stream>>>(O, CS);
        cum2<<<B_, F_, 0, stream>>>(CS);
        cum3<<<B_*NCH_, F_, 0, stream>>>(O, CS, FP);
        norm_k<<<T_, 256, 0, stream>>>(FP);
        update_k<<<(T_*F_)/256, 256, 0, stream>>>(X0, X1, FP);
    }

    concat_k<<<T_, 256, 0, stream>>>(X0, X1, Xcat);
    gemm_k<A_PLAIN, true, EPI_FINAL><<<dim3(T_/BN, CLASSES_/BM), 256, 0, stream>>>(
        out_w, Xcat, out, CLASSES_, T_, 2*F_, nullptr, 2*F_, out_b);
}

// Round 3
// 2386.713 us; speedup vs baseline: 5.1086x; 5.1086x over previous
//
#include <hip/hip_runtime.h>
#include <math.h>

typedef unsigned short u16;
typedef unsigned int   u32;

#define B_ 2
#define S_ 2048
#define F_ 512
#define I_ 1024
#define E_ 8
#define KW_ 7
#define D_ 2
#define CLASSES_ 8192
#define T_ (B_*S_)

typedef __bf16 bf16x8 __attribute__((ext_vector_type(8)));
typedef float  f32x4  __attribute__((ext_vector_type(4)));

__device__ __forceinline__ u16 f2b(float f) {
    u32 x = __float_as_uint(f);
    return (u16)((x + 0x7fffu + ((x >> 16) & 1u)) >> 16);
}
// split fp32 into hi+lo bf16 (v ~= hi + lo, |err| ~ 2^-18 |v|)
__device__ __forceinline__ void fsplit(float v, u16& h, u16& l) {
    u16 hh = f2b(v);
    float hv = __uint_as_float(((u32)hh) << 16);
    h = hh;
    l = f2b(v - hv);
}

#define GLDS16(g, l) __builtin_amdgcn_global_load_lds( \
    (const __attribute__((address_space(1))) u32*)(g), \
    (__attribute__((address_space(3))) u32*)(l), 16, 0, 0)

// ---------------- embed gather (fp32 states) ----------------
__global__ void embed_k(const int* __restrict__ inp, const float* __restrict__ emb,
                        float* __restrict__ X0, float* __restrict__ X1)
{
    int t = blockIdx.x;
    int r = inp[t];
    const float* e = emb + (size_t)r * (2*F_);
    for (int c = threadIdx.x; c < F_; c += 256) {
        X0[(size_t)t*F_ + c] = e[c];
        X1[(size_t)t*F_ + c] = e[F_ + c];
    }
}

// ---------------- gate (fp32) ----------------
__global__ __launch_bounds__(64) void gate_k(const float* __restrict__ X,
                                             const float* __restrict__ GW,
                                             float* __restrict__ G, int W)
{
    __shared__ float xs[1024];
    int t = blockIdx.x;
    const float* xr = X + (size_t)t * W;
    for (int c = threadIdx.x; c < W; c += 64) xs[c] = xr[c];
    __syncthreads();
    int l = threadIdx.x;
    int e = l & 7;
    float p = 0.f;
    for (int f = (l >> 3); f < W; f += 8)
        p += xs[f] * GW[f*E_ + e];
    p += __shfl_xor(p, 8);
    p += __shfl_xor(p, 16);
    p += __shfl_xor(p, 32);
    if (l < 8) G[(size_t)t*E_ + l] = p;
}

// ---------------- top-2 softmax -> dense combine ----------------
__global__ void topk_k(const float* __restrict__ G, float* __restrict__ C)
{
    int t = blockIdx.x * blockDim.x + threadIdx.x;
    if (t >= T_) return;
    float v0 = -3.4e38f, v1 = -3.4e38f; int i0 = 0, i1 = 0;
    #pragma unroll
    for (int e = 0; e < E_; e++) {
        float v = G[(size_t)t*E_ + e];
        if (v > v0)      { v1 = v0; i1 = i0; v0 = v; i0 = e; }
        else if (v > v1) { v1 = v;  i1 = e; }
    }
    float ex = expf(v1 - v0);
    float w0 = 1.f / (1.f + ex);
    float w1 = ex / (1.f + ex);
    #pragma unroll
    for (int e = 0; e < E_; e++)
        C[(size_t)t*E_ + e] = (e == i0) ? w0 : (e == i1) ? w1 : 0.f;
}

// ---- weight transpose: fp32 (R x C) per z -> bf16 hi/lo [c][z*R + r], k-stride LD ----
__global__ __launch_bounds__(256) void transp_k(const float* __restrict__ src0,
                                                u16* __restrict__ dh, u16* __restrict__ dl,
                                                int R, int C, int LD)
{
    __shared__ float tl[32][33];
    int z = blockIdx.z;
    const float* src = src0 + (size_t)z * R * C;
    int coff = z * R;
    int c0 = blockIdx.x * 32, r0 = blockIdx.y * 32;
    int tx = threadIdx.x & 31, ty = threadIdx.x >> 5;
    #pragma unroll
    for (int j = 0; j < 32; j += 8)
        tl[ty + j][tx] = src[(size_t)(r0 + ty + j) * C + c0 + tx];
    __syncthreads();
    #pragma unroll
    for (int j = 0; j < 32; j += 8) {
        u16 h, l; fsplit(tl[tx][ty + j], h, l);
        size_t idx = (size_t)(c0 + ty + j) * LD + coff + r0 + tx;
        dh[idx] = h; dl[idx] = l;
    }
}

// ---- conv weight rearrange: (o,i,k) fp32 -> bf16 hi/lo [o][kc*I + i] ----
__global__ __launch_bounds__(256) void convw_k(const float* __restrict__ src,
                                               u16* __restrict__ dh, u16* __restrict__ dl)
{
    __shared__ float row[KW_*I_];
    int o = blockIdx.x;
    const float* s = src + (size_t)o * (KW_*I_);
    for (int c = threadIdx.x; c < KW_*I_; c += 256) row[c] = s[c];
    __syncthreads();
    size_t base = (size_t)o * (KW_*I_);
    for (int j = threadIdx.x; j < KW_*I_; j += 256) {
        int kc = j >> 10, i = j & 1023;
        u16 h, l; fsplit(row[i*KW_ + kc], h, l);
        dh[base + j] = h; dl[base + j] = l;
    }
}

// ---- out_w fp32 -> bf16 hi/lo ----
__global__ void outw_k(const float* __restrict__ src, u16* __restrict__ dh, u16* __restrict__ dl)
{
    size_t i = ((size_t)blockIdx.x * 256 + threadIdx.x) * 4;
    float4 v = *(const float4*)(src + i);
    ushort4 oh, ol;
    fsplit(v.x, oh.x, ol.x); fsplit(v.y, oh.y, ol.y);
    fsplit(v.z, oh.z, ol.z); fsplit(v.w, oh.w, ol.w);
    *(ushort4*)(dh + i) = oh;
    *(ushort4*)(dl + i) = ol;
}

// =================== split-bf16 3-pass MFMA GEMM, 128x128 tile, BK=64 ===================
// C[m][n] = sum_k A[m][k] * B^T[n][k], A = Ah+Al, B = Bh+Bl (hi/lo bf16).
enum { A_PLAIN=0, A_MOE=1, A_CONV=2 };
enum { EP_RELU=0, EP_F32=1, EP_F32ACC=2, EP_FINAL=3 };

template<int AM, int EP>
__global__ __launch_bounds__(256, 2)
void mgemm(const void* __restrict__ Ap, const void* __restrict__ Ap2,
           const u16* __restrict__ Bh, const u16* __restrict__ Bl,
           void* __restrict__ Cp, int N, int Kd, int lda,
           const float* __restrict__ comb, int segShift, int eoff,
           const float* __restrict__ bias)
{
    __shared__ uint4 ldsv[4096];           // 64 KiB: Ah|Al|Bh|Bl, 16 KiB each
    char* lds = (char*)ldsv;
    const int tid  = threadIdx.x;
    const int lane = tid & 63, wid = tid >> 6;
    const int m0 = blockIdx.y * 128, n0 = blockIdx.x * 128;

    // staging geometry: thread's 16B chunk i -> row, swizzled logical k
    int srow[4], sklog[4];
    #pragma unroll
    for (int i = 0; i < 4; i++) {
        int L = tid * 16 + i * 4096;
        int row = L >> 7;
        srow[i]  = row;
        sklog[i] = ((((L >> 4) & 7) ^ (row & 7)) << 3);
    }

    const u16 *bgh[4], *bgl[4];
    #pragma unroll
    for (int i = 0; i < 4; i++) {
        size_t off = (size_t)(n0 + srow[i]) * Kd + sklog[i];
        bgh[i] = Bh + off; bgl[i] = Bl + off;
    }

    const u16 *agh[4], *agl[4];
    const float *xg[4], *cbp[4];
    int trow[4], srem[4];
    #pragma unroll
    for (int i = 0; i < 4; i++) {
        int t = m0 + srow[i];
        if (AM == A_PLAIN) {
            agh[i] = (const u16*)Ap  + (size_t)t * lda + sklog[i];
            agl[i] = (const u16*)Ap2 + (size_t)t * lda + sklog[i];
        }
        if (AM == A_MOE) {
            xg[i]  = (const float*)Ap + (size_t)t * lda + sklog[i];
            cbp[i] = comb + (size_t)t * E_;
        }
        if (AM == A_CONV) { trow[i] = t; srem[i] = t & (S_-1); }
    }

    // fragment read offsets (swizzle matches staging)
    const int wr = wid >> 1, wc = wid & 1;
    const int l15 = lane & 15, kq = lane >> 4;
    int aoff[4][2], boff[4][2];
    #pragma unroll
    for (int m = 0; m < 4; m++) {
        int ra  = wr*64 + m*16 + l15;
        int rb  = wc*64 + m*16 + l15;
        #pragma unroll
        for (int q = 0; q < 2; q++) {
            int kl = q*4 + kq;
            aoff[m][q] = ra*128 + ((kl ^ (ra & 7)) << 4);
            boff[m][q] = 32768 + rb*128 + ((kl ^ (rb & 7)) << 4);
        }
    }

    f32x4 acc[4][4];
    #pragma unroll
    for (int m = 0; m < 4; m++)
        #pragma unroll
        for (int n = 0; n < 4; n++) acc[m][n] = {0.f, 0.f, 0.f, 0.f};

    for (int k0 = 0; k0 < Kd; k0 += 64) {
        #pragma unroll
        for (int i = 0; i < 4; i++)
            GLDS16(bgh[i] + k0, lds + 32768 + i*4096 + (wid << 10));
        #pragma unroll
        for (int i = 0; i < 4; i++)
            GLDS16(bgl[i] + k0, lds + 49152 + i*4096 + (wid << 10));

        if (AM == A_PLAIN) {
            #pragma unroll
            for (int i = 0; i < 4; i++)
                GLDS16(agh[i] + k0, lds + i*4096 + (wid << 10));
            #pragma unroll
            for (int i = 0; i < 4; i++)
                GLDS16(agl[i] + k0, lds + 16384 + i*4096 + (wid << 10));
        } else if (AM == A_MOE) {
            int e  = (k0 >> segShift) + eoff;
            int fo = k0 & (lda - 1);
            #pragma unroll
            for (int i = 0; i < 4; i++) {
                float cw = cbp[i][e];
                const float* s = xg[i] + fo;
                float4 v0 = *(const float4*)(s);
                float4 v1 = *(const float4*)(s + 4);
                union { u16 u[8]; uint4 q; } H, L;
                fsplit(v0.x*cw, H.u[0], L.u[0]); fsplit(v0.y*cw, H.u[1], L.u[1]);
                fsplit(v0.z*cw, H.u[2], L.u[2]); fsplit(v0.w*cw, H.u[3], L.u[3]);
                fsplit(v1.x*cw, H.u[4], L.u[4]); fsplit(v1.y*cw, H.u[5], L.u[5]);
                fsplit(v1.z*cw, H.u[6], L.u[6]); fsplit(v1.w*cw, H.u[7], L.u[7]);
                *(uint4*)(lds + i*4096 + tid*16) = H.q;
                *(uint4*)(lds + 16384 + i*4096 + tid*16) = L.q;
            }
        } else { // A_CONV: A[t][kc*1024+ch] = H1[t+kc-6][ch], zero when s+kc<6
            #pragma unroll
            for (int i = 0; i < 4; i++) {
                int kk = k0 + sklog[i];
                int kc = kk >> 10, ch = kk & 1023;
                bool ok = (srem[i] + kc) >= 6;
                const float* s = (const float*)Ap + (((size_t)(trow[i] + kc - 6)) << 10) + ch;
                float4 v0 = *(const float4*)(s);
                float4 v1 = *(const float4*)(s + 4);
                if (!ok) { v0 = make_float4(0,0,0,0); v1 = make_float4(0,0,0,0); }
                union { u16 u[8]; uint4 q; } H, L;
                fsplit(v0.x, H.u[0], L.u[0]); fsplit(v0.y, H.u[1], L.u[1]);
                fsplit(v0.z, H.u[2], L.u[2]); fsplit(v0.w, H.u[3], L.u[3]);
                fsplit(v1.x, H.u[4], L.u[4]); fsplit(v1.y, H.u[5], L.u[5]);
                fsplit(v1.z, H.u[6], L.u[6]); fsplit(v1.w, H.u[7], L.u[7]);
                *(uint4*)(lds + i*4096 + tid*16) = H.q;
                *(uint4*)(lds + 16384 + i*4096 + tid*16) = L.q;
            }
        }
        __syncthreads();

        #pragma unroll
        for (int q = 0; q < 2; q++) {
            bf16x8 ah[4], al[4], bh4[4], bl4[4];
            #pragma unroll
            for (int m = 0; m < 4; m++) {
                ah[m] = *(const bf16x8*)(lds + aoff[m][q]);
                al[m] = *(const bf16x8*)(lds + aoff[m][q] + 16384);
            }
            #pragma unroll
            for (int n = 0; n < 4; n++) {
                bh4[n] = *(const bf16x8*)(lds + boff[n][q]);
                bl4[n] = *(const bf16x8*)(lds + boff[n][q] + 16384);
            }
            #pragma unroll
            for (int m = 0; m < 4; m++)
                #pragma unroll
                for (int n = 0; n < 4; n++) {
                    acc[m][n] = __builtin_amdgcn_mfma_f32_16x16x32_bf16(ah[m], bh4[n], acc[m][n], 0, 0, 0);
                    acc[m][n] = __builtin_amdgcn_mfma_f32_16x16x32_bf16(al[m], bh4[n], acc[m][n], 0, 0, 0);
                    acc[m][n] = __builtin_amdgcn_mfma_f32_16x16x32_bf16(ah[m], bl4[n], acc[m][n], 0, 0, 0);
                }
        }
        __syncthreads();
    }

    // epilogue: C/D layout col=lane&15, row=(lane>>4)*4+reg
    #pragma unroll
    for (int m = 0; m < 4; m++) {
        #pragma unroll
        for (int n = 0; n < 4; n++) {
            f32x4 v = acc[m][n];
            int row0 = m0 + wr*64 + m*16 + (lane >> 4)*4;
            int col  = n0 + wc*64 + n*16 + l15;
            #pragma unroll
            for (int j = 0; j < 4; j++) {
                float x = v[j];
                int r = row0 + j;
                if (EP == EP_RELU) {
                    ((float*)Cp)[(size_t)r * N + col] = fmaxf(x, 0.f);
                } else if (EP == EP_F32) {
                    ((float*)Cp)[(size_t)r * N + col] = x;
                } else if (EP == EP_F32ACC) {
                    ((float*)Cp)[(size_t)r * N + col] += x;
                } else { // EP_FINAL
                    x += bias[r];
                    int b = col >> 11, s = col & (S_-1);
                    ((float*)Cp)[(((size_t)(b*CLASSES_ + r)) << 11) + s] = x;
                }
            }
        }
    }
}

// ---------------- chunked cumsum ----------------
#define SC_ 128
#define NCH_ (S_/SC_)
__global__ void cum1(const float* __restrict__ O, float* __restrict__ CS)
{
    int blk = blockIdx.x;
    int b = blk / NCH_, ch = blk % NCH_;
    int c = threadIdx.x;
    int s0 = ch * SC_;
    const float* base = O + ((size_t)(b*S_ + s0)) * (3*F_) + c;
    float sum = 0.f;
    for (int s = 0; s < SC_; s++) sum += base[(size_t)s * (3*F_)];
    CS[(size_t)blk * F_ + c] = sum;
}
__global__ void cum2(float* __restrict__ CS)
{
    int b = blockIdx.x; int c = threadIdx.x;
    float run = 0.f;
    for (int ch = 0; ch < NCH_; ch++) {
        size_t idx = (size_t)(b*NCH_ + ch) * F_ + c;
        float v = CS[idx]; CS[idx] = run; run += v;
    }
}
__global__ void cum3(const float* __restrict__ O, const float* __restrict__ CS,
                     float* __restrict__ FP)
{
    int blk = blockIdx.x;
    int b = blk / NCH_, ch = blk % NCH_;
    int c = threadIdx.x;
    float run = CS[(size_t)blk * F_ + c];
    int s0 = ch * SC_;
    for (int s = s0; s < s0 + SC_; s++) {
        size_t t = (size_t)b * S_ + s;
        const float* row = O + t * (3*F_);
        run += row[c];
        FP[t*F_ + c] = run / (float)(s + 1) * row[F_ + c] + row[2*F_ + c];
    }
}

// ---------------- channel norm ----------------
__global__ __launch_bounds__(256) void norm_k(float* __restrict__ FP)
{
    __shared__ float sb[4];
    int t = blockIdx.x;
    float* row = FP + (size_t)t * F_;
    int tid = threadIdx.x;
    float v0 = row[tid], v1 = row[tid + 256];
    float s = v0 + v1;
    #pragma unroll
    for (int off = 32; off; off >>= 1) s += __shfl_xor(s, off);
    int w = tid >> 6;
    if ((tid & 63) == 0) sb[w] = s;
    __syncthreads();
    float mean = (sb[0] + sb[1] + sb[2] + sb[3]) * (1.0f / F_);
    v0 -= mean; v1 -= mean;
    float q = v0*v0 + v1*v1;
    #pragma unroll
    for (int off = 32; off; off >>= 1) q += __shfl_xor(q, off);
    __syncthreads();
    if ((tid & 63) == 0) sb[w] = q;
    __syncthreads();
    float ss = sb[0] + sb[1] + sb[2] + sb[3];
    float denom = sqrtf(ss) * 0.04419417382415922f + 1e-5f;
    float sc = 0.70710678118654752f / denom;
    row[tid] = v0 * sc; row[tid + 256] = v1 * sc;
}

// ---------------- recurrence ----------------
__global__ void update_k(float* __restrict__ X0, float* __restrict__ X1,
                         const float* __restrict__ FP)
{
    int i = blockIdx.x * 256 + threadIdx.x;
    float a = 0.9f * X0[i] + 0.1f * FP[i];
    X0[i] = a;
    X1[i] = X1[i] + a;
}

// ---------------- concat -> bf16 hi/lo ----------------
__global__ void concat_k(const float* __restrict__ X0, const float* __restrict__ X1,
                         u16* __restrict__ Xh, u16* __restrict__ Xl)
{
    int t = blockIdx.x;
    for (int c = threadIdx.x; c < F_; c += 256) {
        u16 h, l;
        fsplit(X0[(size_t)t*F_ + c], h, l);
        Xh[(size_t)t*(2*F_) + c] = h;      Xl[(size_t)t*(2*F_) + c] = l;
        fsplit(X1[(size_t)t*F_ + c], h, l);
        Xh[(size_t)t*(2*F_) + F_ + c] = h; Xl[(size_t)t*(2*F_) + F_ + c] = l;
    }
}

extern "C" void kernel_launch(void* const* d_in, const int* in_sizes, int n_in,
                              void* d_out, int out_size, void* d_ws, size_t ws_size,
                              hipStream_t stream)
{
    const int*   inp    = (const int*)  d_in[0];
    const float* embed  = (const float*)d_in[1];
    const float* gin_w  = (const float*)d_in[2];
    const float* w_in   = (const float*)d_in[3];
    const float* conv_w = (const float*)d_in[4];
    const float* gout_w = (const float*)d_in[5];
    const float* w_out  = (const float*)d_in[6];
    const float* out_w  = (const float*)d_in[7];
    const float* out_b  = (const float*)d_in[8];
    float* out = (float*)d_out;

    char* w = (char*)d_ws;
    auto alloc = [&](size_t bytes) { char* r = w; w += (bytes + 255) & ~(size_t)255; return r; };
    float* X0  = (float*)alloc((size_t)T_*F_*4);
    float* X1  = (float*)alloc((size_t)T_*F_*4);
    char*  H1r = alloc((size_t)T_*I_*4);          // H1 fp32; after loop: Xcat hi|lo
    char*  HCr = alloc((size_t)T_*I_*4);          // HC fp32; after loop: OutW hi
    char*  Or  = alloc((size_t)T_*3*F_*4);        // O  fp32; after loop: OutW lo
    float* FP  = (float*)alloc((size_t)T_*F_*4);
    float* CS  = (float*)alloc((size_t)B_*NCH_*F_*4);
    float* G   = (float*)alloc((size_t)T_*E_*4);
    float* Cmb = (float*)alloc((size_t)T_*E_*4);
    u16*   Wh  = (u16*)alloc((size_t)I_*KW_*I_*2);   // max family: conv 1024x7168
    u16*   Wl  = (u16*)alloc((size_t)I_*KW_*I_*2);

    float* H1 = (float*)H1r;
    float* HC = (float*)HCr;
    float* O  = (float*)Or;

    embed_k<<<T_, 256, 0, stream>>>(inp, embed, X0, X1);

    for (int d = 0; d < D_; ++d) {
        gate_k<<<T_, 64, 0, stream>>>(X1, gin_w + (size_t)d*F_*E_, G, F_);
        topk_k<<<T_/256, 256, 0, stream>>>(G, Cmb);
        transp_k<<<dim3(I_/32, F_/32, E_), 256, 0, stream>>>(
            w_in + (size_t)d*E_*F_*I_, Wh, Wl, F_, I_, E_*F_);
        mgemm<A_MOE, EP_RELU><<<dim3(I_/128, T_/128), 256, 0, stream>>>(
            X1, nullptr, Wh, Wl, H1, I_, E_*F_, F_, Cmb, 9, 0, nullptr);

        convw_k<<<I_, 256, 0, stream>>>(conv_w + (size_t)d*I_*I_*KW_, Wh, Wl);
        mgemm<A_CONV, EP_RELU><<<dim3(I_/128, T_/128), 256, 0, stream>>>(
            H1, nullptr, Wh, Wl, HC, I_, KW_*I_, 0, nullptr, 0, 0, nullptr);

        gate_k<<<T_, 64, 0, stream>>>(HC, gout_w + (size_t)d*I_*E_, G, I_);
        topk_k<<<T_/256, 256, 0, stream>>>(G, Cmb);
        // MoE2 in two 4-expert chunks (keeps transposed weights <= conv-size buffer)
        for (int c = 0; c < 2; ++c) {
            transp_k<<<dim3((3*F_)/32, I_/32, 4), 256, 0, stream>>>(
                w_out + (size_t)d*E_*I_*(3*F_) + (size_t)c*4*I_*(3*F_), Wh, Wl, I_, 3*F_, 4*I_);
            if (c == 0)
                mgemm<A_MOE, EP_F32><<<dim3((3*F_)/128, T_/128), 256, 0, stream>>>(
                    HC, nullptr, Wh, Wl, O, 3*F_, 4*I_, I_, Cmb, 10, 0, nullptr);
            else
                mgemm<A_MOE, EP_F32ACC><<<dim3((3*F_)/128, T_/128), 256, 0, stream>>>(
                    HC, nullptr, Wh, Wl, O, 3*F_, 4*I_, I_, Cmb, 10, 4, nullptr);
        }

        cum1<<<B_*NCH_, F_, 0, stream>>>(O, CS);
        cum2<<<B_, F_, 0, stream>>>(CS);
        cum3<<<B_*NCH_, F_, 0, stream>>>(O, CS, FP);
        norm_k<<<T_, 256, 0, stream>>>(FP);
        update_k<<<(T_*F_)/256, 256, 0, stream>>>(X0, X1, FP);
    }

    // after the loop: reuse dead regions for final-GEMM operands
    u16* Xch = (u16*)H1r;
    u16* Xcl = (u16*)(H1r + (size_t)T_*(2*F_)*2);
    u16* OWh = (u16*)HCr;
    u16* OWl = (u16*)Or;

    concat_k<<<T_, 256, 0, stream>>>(X0, X1, Xch, Xcl);
    outw_k<<<(CLASSES_*2*F_)/1024, 256, 0, stream>>>(out_w, OWh, OWl);
    mgemm<A_PLAIN, EP_FINAL><<<dim3(T_/128, CLASSES_/128), 256, 0, stream>>>(
        OWh, OWl, Xch, Xcl, out, T_, 2*F_, 2*F_, nullptr, 0, 0, out_b);
}

// Round 4
// 1877.468 us; speedup vs baseline: 6.4943x; 1.2712x over previous
//
#include <hip/hip_runtime.h>
#include <math.h>

typedef unsigned short u16;
typedef unsigned int   u32;

#define B_ 2
#define S_ 2048
#define F_ 512
#define I_ 1024
#define E_ 8
#define KW_ 7
#define D_ 2
#define CLASSES_ 8192
#define T_ (B_*S_)
#define SP_ (S_+6)
#define NSLOT_ 9216
#define GMAX_ 72

typedef __bf16 bf16x8 __attribute__((ext_vector_type(8)));
typedef float  f32x4  __attribute__((ext_vector_type(4)));

__device__ __forceinline__ u16 f2b(float f) {
    u32 x = __float_as_uint(f);
    return (u16)((x + 0x7fffu + ((x >> 16) & 1u)) >> 16);
}
__device__ __forceinline__ void fsplit(float v, u16& h, u16& l) {
    u16 hh = f2b(v);
    float hv = __uint_as_float(((u32)hh) << 16);
    h = hh;
    l = f2b(v - hv);
}

#define GLDS16(g, l) __builtin_amdgcn_global_load_lds( \
    (const __attribute__((address_space(1))) u32*)(g), \
    (__attribute__((address_space(3))) u32*)(l), 16, 0, 0)

// ---------------- misc small kernels ----------------
__global__ void embed_k(const int* __restrict__ inp, const float* __restrict__ emb,
                        float* __restrict__ X0, float* __restrict__ X1)
{
    int t = blockIdx.x;
    int r = inp[t];
    const float* e = emb + (size_t)r * (2*F_);
    for (int c = threadIdx.x; c < F_; c += 256) {
        X0[(size_t)t*F_ + c] = e[c];
        X1[(size_t)t*F_ + c] = e[F_ + c];
    }
}

__global__ void zero_k(float4* __restrict__ p, int n)
{
    for (int i = blockIdx.x*256 + threadIdx.x; i < n; i += gridDim.x*256)
        p[i] = make_float4(0.f,0.f,0.f,0.f);
}

__global__ __launch_bounds__(64) void gate_k(const float* __restrict__ X,
                                             const float* __restrict__ GW,
                                             float* __restrict__ G, int W)
{
    __shared__ float xs[1024];
    int t = blockIdx.x;
    const float* xr = X + (size_t)t * W;
    for (int c = threadIdx.x; c < W; c += 64) xs[c] = xr[c];
    __syncthreads();
    int l = threadIdx.x;
    int e = l & 7;
    float p = 0.f;
    for (int f = (l >> 3); f < W; f += 8)
        p += xs[f] * GW[f*E_ + e];
    p += __shfl_xor(p, 8);
    p += __shfl_xor(p, 16);
    p += __shfl_xor(p, 32);
    if (l < 8) G[(size_t)t*E_ + l] = p;
}

__global__ void init_slots_k(int* __restrict__ stok, float* __restrict__ sw, int* __restrict__ cnt)
{
    int i = blockIdx.x*256 + threadIdx.x;
    if (i < NSLOT_) { stok[i] = 0; sw[i] = 0.f; }
    if (i < E_) cnt[i] = 0;
}

__global__ void topk2_k(const float* __restrict__ G, int2* __restrict__ e2,
                        float2* __restrict__ w2, int* __restrict__ cnt)
{
    int t = blockIdx.x * 256 + threadIdx.x;
    if (t >= T_) return;
    float v0 = -3.4e38f, v1 = -3.4e38f; int i0 = 0, i1 = 0;
    #pragma unroll
    for (int e = 0; e < E_; e++) {
        float v = G[(size_t)t*E_ + e];
        if (v > v0)      { v1 = v0; i1 = i0; v0 = v; i0 = e; }
        else if (v > v1) { v1 = v;  i1 = e; }
    }
    float ex = expf(v1 - v0);
    float w0 = 1.f / (1.f + ex);
    float w1 = ex / (1.f + ex);
    e2[t] = make_int2(i0, i1);
    w2[t] = make_float2(w0, w1);
    atomicAdd(&cnt[i0], 1);
    atomicAdd(&cnt[i1], 1);
}

__global__ void sched_k(const int* __restrict__ cnt, int* __restrict__ pos,
                        int4* __restrict__ s0, int4* __restrict__ s1, int split)
{
    if (blockIdx.x || threadIdx.x) return;
    int poff = 0, i0 = 0, i1 = 0;
    for (int e = 0; e < E_; e++) {
        pos[e] = poff;
        int nb = (cnt[e] + 127) >> 7;
        for (int j = 0; j < nb; j++) {
            int4 en = make_int4(poff + j*128, (e < split ? e : e - split), 1, 0);
            if (e < split) s0[i0++] = en; else s1[i1++] = en;
        }
        poff += nb << 7;
    }
    while (i0 < GMAX_) s0[i0++] = make_int4(0,0,0,0);
    if (split < E_) while (i1 < GMAX_) s1[i1++] = make_int4(0,0,0,0);
}

__global__ void scatter_k(const int2* __restrict__ e2, const float2* __restrict__ w2,
                          int* __restrict__ pos, int* __restrict__ stok, float* __restrict__ sw)
{
    int t = blockIdx.x * 256 + threadIdx.x;
    if (t >= T_) return;
    int2 e = e2[t]; float2 w = w2[t];
    int p0 = atomicAdd(&pos[e.x], 1);
    stok[p0] = t; sw[p0] = w.x;
    int p1 = atomicAdd(&pos[e.y], 1);
    stok[p1] = t; sw[p1] = w.y;
}

// ---- weight transpose: src fp32 (R x C) per z -> dst bf16 hi/lo [z][C][R] ----
__global__ __launch_bounds__(256) void transp_k(const float* __restrict__ src0,
                                                u16* __restrict__ dh, u16* __restrict__ dl,
                                                int R, int C)
{
    __shared__ float tl[32][33];
    int z = blockIdx.z;
    const float* src = src0 + (size_t)z * R * C;
    size_t dbase = (size_t)z * R * C;
    int c0 = blockIdx.x * 32, r0 = blockIdx.y * 32;
    int tx = threadIdx.x & 31, ty = threadIdx.x >> 5;
    #pragma unroll
    for (int j = 0; j < 32; j += 8)
        tl[ty + j][tx] = src[(size_t)(r0 + ty + j) * C + c0 + tx];
    __syncthreads();
    #pragma unroll
    for (int j = 0; j < 32; j += 8) {
        u16 h, l; fsplit(tl[tx][ty + j], h, l);
        size_t idx = dbase + (size_t)(c0 + ty + j) * R + r0 + tx;
        dh[idx] = h; dl[idx] = l;
    }
}

// ---- conv weight: (o,i,k) fp32 -> bf16 hi/lo [o][kc*I + i] ----
__global__ __launch_bounds__(256) void convw_k(const float* __restrict__ src,
                                               u16* __restrict__ dh, u16* __restrict__ dl)
{
    __shared__ float row[KW_*I_];
    int o = blockIdx.x;
    const float* s = src + (size_t)o * (KW_*I_);
    for (int c = threadIdx.x; c < KW_*I_; c += 256) row[c] = s[c];
    __syncthreads();
    size_t base = (size_t)o * (KW_*I_);
    for (int j = threadIdx.x; j < KW_*I_; j += 256) {
        int kc = j >> 10, i = j & 1023;
        u16 h, l; fsplit(row[i*KW_ + kc], h, l);
        dh[base + j] = h; dl[base + j] = l;
    }
}

__global__ void outw_k(const float* __restrict__ src, u16* __restrict__ dh, u16* __restrict__ dl)
{
    size_t i = ((size_t)blockIdx.x * 256 + threadIdx.x) * 4;
    float4 v = *(const float4*)(src + i);
    ushort4 oh, ol;
    fsplit(v.x, oh.x, ol.x); fsplit(v.y, oh.y, ol.y);
    fsplit(v.z, oh.z, ol.z); fsplit(v.w, oh.w, ol.w);
    *(ushort4*)(dh + i) = oh;
    *(ushort4*)(dl + i) = ol;
}

// ---- H1acc -> relu -> split -> padded hi/lo ----
__global__ void hsplit_k(const float* __restrict__ H, u16* __restrict__ ph, u16* __restrict__ pl)
{
    int gid = blockIdx.x*256 + threadIdx.x;
    int eb = gid * 4;
    int t = eb >> 10, c = eb & 1023;
    float4 v = *(const float4*)(H + eb);
    ushort4 hh, ll;
    fsplit(fmaxf(v.x,0.f), hh.x, ll.x); fsplit(fmaxf(v.y,0.f), hh.y, ll.y);
    fsplit(fmaxf(v.z,0.f), hh.z, ll.z); fsplit(fmaxf(v.w,0.f), hh.w, ll.w);
    size_t row = (size_t)(t >> 11)*SP_ + 6 + (t & (S_-1));
    *(ushort4*)(ph + (row << 10) + c) = hh;
    *(ushort4*)(pl + (row << 10) + c) = ll;
}

__global__ void hpadzero_k(u16* __restrict__ ph, u16* __restrict__ pl)
{
    int idx = blockIdx.x*256 + threadIdx.x;   // B_*6*I_
    int b = idx / (6*I_);
    int rem = idx - b*(6*I_);
    size_t a = ((size_t)b*SP_ + (rem >> 10))*I_ + (rem & 1023);
    ph[a] = 0; pl[a] = 0;
}

// =================== split-bf16 MFMA GEMM, 128xTN tile, BK=32, double-buffered ===================
enum { A_SPLIT=0, A_CONV=1, A_GATHER=2, A_GATHER2=3 };
enum { EP_RELU_SPLIT=0, EP_SCATTER=1, EP_FINAL=2 };

template<int AM, int EP, int TN, int PASSES>
__global__ __launch_bounds__(256, (TN==64?3:2))
void mgemm(const void* __restrict__ A1, const void* __restrict__ A2,
           const u16* __restrict__ Bh, const u16* __restrict__ Bl,
           float* __restrict__ Cf, u16* __restrict__ Co1, u16* __restrict__ Co2,
           int N, int Kd,
           const int4* __restrict__ sched, const int* __restrict__ stok,
           const float* __restrict__ sw, const float* __restrict__ bias)
{
    constexpr int ACCM = (TN==128 ? 4 : 2);
    constexpr int WM   = (TN==128 ? 64 : 32);
    constexpr int NBCH = TN/64;
    constexpr int OAL  = 8192;
    constexpr int OBH  = (PASSES==3 ? 16384 : 8192);
    constexpr int TNB  = TN*64;
    constexpr int OBL  = OBH + TNB;
    constexpr int SB   = OBH + TNB*(PASSES==3 ? 2 : 1);
    __shared__ uint4 ldsv[2*SB/16];
    char* lds = (char*)ldsv;

    const int tid  = threadIdx.x;
    const int lane = tid & 63, wid = tid >> 6;
    const int n0 = blockIdx.x * TN;

    int slot0 = 0, m0 = 0;
    const u16 *bhb = Bh, *blb = Bl;
    if (AM == A_GATHER || AM == A_GATHER2) {
        int4 sc = sched[blockIdx.y];
        if (!sc.z) return;
        slot0 = sc.x;
        bhb = Bh + (size_t)sc.y * N * Kd;
        blb = Bl + (size_t)sc.y * N * Kd;
    } else {
        m0 = blockIdx.y * 128;
    }

    // staging geometry
    int srow[2], klog[2];
    #pragma unroll
    for (int c = 0; c < 2; c++) {
        int row = (tid >> 2) + c*64;
        srow[c] = row;
        klog[c] = ((tid & 3) ^ ((row >> 1) & 3)) << 3;
    }

    const u16 *bgh[2], *bgl[2];
    #pragma unroll
    for (int c = 0; c < NBCH; c++) {
        size_t off = (size_t)(n0 + srow[c]) * Kd + klog[c];
        bgh[c] = bhb + off;
        bgl[c] = blb + off;
    }

    const u16 *a1p[2], *a2p[2];
    const float* afp[2];
    #pragma unroll
    for (int c = 0; c < 2; c++) {
        if (AM == A_SPLIT) {
            size_t off = (size_t)(m0 + srow[c]) * Kd + klog[c];
            a1p[c] = (const u16*)A1 + off;
            a2p[c] = (const u16*)A2 + off;
        } else if (AM == A_CONV) {
            int t = m0 + srow[c];
            size_t rb = ((size_t)(t >> 11)*SP_ + (t & (S_-1))) << 10;
            a1p[c] = (const u16*)A1 + rb + klog[c];
            a2p[c] = (const u16*)A2 + rb + klog[c];
        } else {
            int tk = stok[slot0 + srow[c]];
            if (AM == A_GATHER2) {
                size_t off = (size_t)tk * Kd + klog[c];
                a1p[c] = (const u16*)A1 + off;
                a2p[c] = (const u16*)A2 + off;
            } else {
                afp[c] = (const float*)A1 + (size_t)tk * Kd + klog[c];
            }
        }
    }

    // fragment read offsets
    const int wr = (TN==128 ? (wid >> 1) : wid);
    const int wc = (TN==128 ? (wid & 1) : 0);
    const int l15 = lane & 15, kq = lane >> 4;
    int aoff[ACCM], boff[4];
    #pragma unroll
    for (int m = 0; m < ACCM; m++) {
        int ra = wr*WM + m*16 + l15;
        aoff[m] = ra*64 + ((kq ^ ((ra >> 1) & 3)) << 4);
    }
    #pragma unroll
    for (int n = 0; n < 4; n++) {
        int rb = wc*64 + n*16 + l15;
        boff[n] = rb*64 + ((kq ^ ((rb >> 1) & 3)) << 4);
    }

    f32x4 acc[ACCM][4];
    #pragma unroll
    for (int m = 0; m < ACCM; m++)
        #pragma unroll
        for (int n = 0; n < 4; n++) acc[m][n] = {0.f,0.f,0.f,0.f};

    const int nt = Kd >> 5;

#define STAGE_GL(K0, BB)                                                        \
    {                                                                           \
        _Pragma("unroll")                                                       \
        for (int c = 0; c < NBCH; c++) {                                        \
            GLDS16(bgh[c] + (K0), lds + (BB) + OBH + c*4096 + (wid<<10));       \
            if (PASSES == 3)                                                    \
                GLDS16(bgl[c] + (K0), lds + (BB) + OBL + c*4096 + (wid<<10));   \
        }                                                                       \
        if (AM != A_GATHER) {                                                   \
            _Pragma("unroll")                                                   \
            for (int c = 0; c < 2; c++) {                                       \
                GLDS16(a1p[c] + (K0), lds + (BB) + c*4096 + (wid<<10));         \
                if (PASSES == 3)                                                \
                    GLDS16(a2p[c] + (K0), lds + (BB) + OAL + c*4096 + (wid<<10)); \
            }                                                                   \
        }                                                                       \
    }

#define GATHER_WRITE(BB, V0, V1, CC)                                            \
    {                                                                           \
        union { u16 u[8]; uint4 q; } Hh, Ll;                                    \
        fsplit((V0).x, Hh.u[0], Ll.u[0]); fsplit((V0).y, Hh.u[1], Ll.u[1]);     \
        fsplit((V0).z, Hh.u[2], Ll.u[2]); fsplit((V0).w, Hh.u[3], Ll.u[3]);     \
        fsplit((V1).x, Hh.u[4], Ll.u[4]); fsplit((V1).y, Hh.u[5], Ll.u[5]);     \
        fsplit((V1).z, Hh.u[6], Ll.u[6]); fsplit((V1).w, Hh.u[7], Ll.u[7]);     \
        *(uint4*)(lds + (BB) + (CC)*4096 + tid*16) = Hh.q;                      \
        if (PASSES == 3)                                                        \
            *(uint4*)(lds + (BB) + OAL + (CC)*4096 + tid*16) = Ll.q;            \
    }

    // prologue: stage tile 0 into buffer 0
    STAGE_GL(0, 0);
    if (AM == A_GATHER) {
        float4 p00 = *(const float4*)(afp[0]);
        float4 p01 = *(const float4*)(afp[0] + 4);
        float4 p10 = *(const float4*)(afp[1]);
        float4 p11 = *(const float4*)(afp[1] + 4);
        GATHER_WRITE(0, p00, p01, 0);
        GATHER_WRITE(0, p10, p11, 1);
    }
    __syncthreads();

    for (int it = 0; it < nt; ++it) {
        const int bb = (it & 1) * SB;
        const int nb = SB - bb;
        const bool more = (it + 1) < nt;
        float4 g00, g01, g10, g11;
        if (more) {
            int k1 = (it + 1) << 5;
            STAGE_GL(k1, nb);
            if (AM == A_GATHER) {
                g00 = *(const float4*)(afp[0] + k1);
                g01 = *(const float4*)(afp[0] + k1 + 4);
                g10 = *(const float4*)(afp[1] + k1);
                g11 = *(const float4*)(afp[1] + k1 + 4);
            }
        }
        // compute on bb
        {
            bf16x8 ah[ACCM], al[ACCM], bhf[4], blf[4];
            #pragma unroll
            for (int m = 0; m < ACCM; m++) {
                ah[m] = *(const bf16x8*)(lds + bb + aoff[m]);
                if (PASSES == 3) al[m] = *(const bf16x8*)(lds + bb + OAL + aoff[m]);
            }
            #pragma unroll
            for (int n = 0; n < 4; n++) {
                bhf[n] = *(const bf16x8*)(lds + bb + OBH + boff[n]);
                if (PASSES == 3) blf[n] = *(const bf16x8*)(lds + bb + OBL + boff[n]);
            }
            #pragma unroll
            for (int m = 0; m < ACCM; m++)
                #pragma unroll
                for (int n = 0; n < 4; n++) {
                    acc[m][n] = __builtin_amdgcn_mfma_f32_16x16x32_bf16(ah[m], bhf[n], acc[m][n], 0, 0, 0);
                    if (PASSES == 3) {
                        acc[m][n] = __builtin_amdgcn_mfma_f32_16x16x32_bf16(al[m], bhf[n], acc[m][n], 0, 0, 0);
                        acc[m][n] = __builtin_amdgcn_mfma_f32_16x16x32_bf16(ah[m], blf[n], acc[m][n], 0, 0, 0);
                    }
                }
        }
        if (more && AM == A_GATHER) {
            GATHER_WRITE(nb, g00, g01, 0);
            GATHER_WRITE(nb, g10, g11, 1);
        }
        __syncthreads();
    }

    // epilogue: C/D layout col=lane&15, row=(lane>>4)*4+reg
    #pragma unroll
    for (int m = 0; m < ACCM; m++) {
        #pragma unroll
        for (int n = 0; n < 4; n++) {
            f32x4 v = acc[m][n];
            int rl0 = wr*WM + m*16 + (lane >> 4)*4;
            int col = n0 + wc*64 + n*16 + l15;
            #pragma unroll
            for (int j = 0; j < 4; j++) {
                float x = v[j];
                int rl = rl0 + j;
                if (EP == EP_SCATTER) {
                    int tt = stok[slot0 + rl];
                    float ww = sw[slot0 + rl];
                    atomicAdd(&Cf[(size_t)tt * N + col], ww * x);
                } else if (EP == EP_RELU_SPLIT) {
                    int r = m0 + rl;
                    float y = fmaxf(x, 0.f);
                    size_t idx = (size_t)r * N + col;
                    Cf[idx] = y;
                    u16 h, l; fsplit(y, h, l);
                    Co1[idx] = h; Co2[idx] = l;
                } else { // EP_FINAL
                    int r = m0 + rl;
                    x += bias[r];
                    int b = col >> 11, s = col & (S_-1);
                    Cf[(((size_t)(b*CLASSES_ + r)) << 11) + s] = x;
                }
            }
        }
    }
#undef STAGE_GL
#undef GATHER_WRITE
}

// ---------------- chunked cumsum ----------------
#define SC_ 128
#define NCH_ (S_/SC_)
__global__ void cum1(const float* __restrict__ O, float* __restrict__ CS)
{
    int blk = blockIdx.x;
    int b = blk / NCH_, ch = blk % NCH_;
    int c = threadIdx.x;
    int s0 = ch * SC_;
    const float* base = O + ((size_t)(b*S_ + s0)) * (3*F_) + c;
    float sum = 0.f;
    for (int s = 0; s < SC_; s++) sum += base[(size_t)s * (3*F_)];
    CS[(size_t)blk * F_ + c] = sum;
}
__global__ void cum2(float* __restrict__ CS)
{
    int b = blockIdx.x; int c = threadIdx.x;
    float run = 0.f;
    for (int ch = 0; ch < NCH_; ch++) {
        size_t idx = (size_t)(b*NCH_ + ch) * F_ + c;
        float v = CS[idx]; CS[idx] = run; run += v;
    }
}
__global__ void cum3(const float* __restrict__ O, const float* __restrict__ CS,
                     float* __restrict__ FP)
{
    int blk = blockIdx.x;
    int b = blk / NCH_, ch = blk % NCH_;
    int c = threadIdx.x;
    float run = CS[(size_t)blk * F_ + c];
    int s0 = ch * SC_;
    for (int s = s0; s < s0 + SC_; s++) {
        size_t t = (size_t)b * S_ + s;
        const float* row = O + t * (3*F_);
        run += row[c];
        FP[t*F_ + c] = run / (float)(s + 1) * row[F_ + c] + row[2*F_ + c];
    }
}

__global__ __launch_bounds__(256) void norm_k(float* __restrict__ FP)
{
    __shared__ float sb[4];
    int t = blockIdx.x;
    float* row = FP + (size_t)t * F_;
    int tid = threadIdx.x;
    float v0 = row[tid], v1 = row[tid + 256];
    float s = v0 + v1;
    #pragma unroll
    for (int off = 32; off; off >>= 1) s += __shfl_xor(s, off);
    int w = tid >> 6;
    if ((tid & 63) == 0) sb[w] = s;
    __syncthreads();
    float mean = (sb[0] + sb[1] + sb[2] + sb[3]) * (1.0f / F_);
    v0 -= mean; v1 -= mean;
    float q = v0*v0 + v1*v1;
    #pragma unroll
    for (int off = 32; off; off >>= 1) q += __shfl_xor(q, off);
    __syncthreads();
    if ((tid & 63) == 0) sb[w] = q;
    __syncthreads();
    float ss = sb[0] + sb[1] + sb[2] + sb[3];
    float denom = sqrtf(ss) * 0.04419417382415922f + 1e-5f;
    float sc = 0.70710678118654752f / denom;
    row[tid] = v0 * sc; row[tid + 256] = v1 * sc;
}

__global__ void update_k(float* __restrict__ X0, float* __restrict__ X1,
                         const float* __restrict__ FP)
{
    int i = blockIdx.x * 256 + threadIdx.x;
    float a = 0.9f * X0[i] + 0.1f * FP[i];
    X0[i] = a;
    X1[i] = X1[i] + a;
}

__global__ void concat_k(const float* __restrict__ X0, const float* __restrict__ X1,
                         u16* __restrict__ Xh, u16* __restrict__ Xl)
{
    int t = blockIdx.x;
    for (int c = threadIdx.x; c < F_; c += 256) {
        u16 h, l;
        fsplit(X0[(size_t)t*F_ + c], h, l);
        Xh[(size_t)t*(2*F_) + c] = h;      Xl[(size_t)t*(2*F_) + c] = l;
        fsplit(X1[(size_t)t*F_ + c], h, l);
        Xh[(size_t)t*(2*F_) + F_ + c] = h; Xl[(size_t)t*(2*F_) + F_ + c] = l;
    }
}

extern "C" void kernel_launch(void* const* d_in, const int* in_sizes, int n_in,
                              void* d_out, int out_size, void* d_ws, size_t ws_size,
                              hipStream_t stream)
{
    const int*   inp    = (const int*)  d_in[0];
    const float* embed  = (const float*)d_in[1];
    const float* gin_w  = (const float*)d_in[2];
    const float* w_in   = (const float*)d_in[3];
    const float* conv_w = (const float*)d_in[4];
    const float* gout_w = (const float*)d_in[5];
    const float* w_out  = (const float*)d_in[6];
    const float* out_w  = (const float*)d_in[7];
    const float* out_b  = (const float*)d_in[8];
    float* out = (float*)d_out;

    char* w = (char*)d_ws;
    auto alloc = [&](size_t bytes) { char* r = w; w += (bytes + 255) & ~(size_t)255; return r; };
    float* X0    = (float*)alloc((size_t)T_*F_*4);
    float* X1    = (float*)alloc((size_t)T_*F_*4);
    u16*   Hpadh = (u16*)  alloc((size_t)B_*SP_*I_*2);      // adjacent pair (reused as OutWl)
    u16*   Hpadl = (u16*)  alloc((size_t)B_*SP_*I_*2);
    u16*   HCh   = (u16*)  alloc((size_t)T_*I_*2);
    u16*   HCl   = (u16*)  alloc((size_t)T_*I_*2);
    float* FP    = (float*)alloc((size_t)T_*F_*4);
    float* CS    = (float*)alloc((size_t)B_*NCH_*F_*4);
    char*  ar1   = alloc((size_t)T_*3*F_*4);                // H1acc / O / Xcat h,l
    char*  ar2   = alloc((size_t)T_*I_*4);                  // HC / OutWh
    u16*   Wh    = (u16*)  alloc((size_t)I_*KW_*I_*2);
    u16*   Wl    = (u16*)  alloc((size_t)I_*KW_*I_*2);
    float* G     = (float*)alloc((size_t)T_*E_*4);
    int2*  e2    = (int2*) alloc((size_t)T_*8);
    float2* w2   = (float2*)alloc((size_t)T_*8);
    int*   stok  = (int*)  alloc((size_t)NSLOT_*4);
    float* sw    = (float*)alloc((size_t)NSLOT_*4);
    int*   cnt   = (int*)  alloc(64);
    int*   pos   = (int*)  alloc(64);
    int4*  s0    = (int4*) alloc((size_t)GMAX_*16);
    int4*  s1    = (int4*) alloc((size_t)GMAX_*16);

    float* H1acc = (float*)ar1;
    float* O     = (float*)ar1;
    float* HC    = (float*)ar2;

    embed_k<<<T_, 256, 0, stream>>>(inp, embed, X0, X1);
    hpadzero_k<<<(B_*6*I_)/256, 256, 0, stream>>>(Hpadh, Hpadl);

    for (int d = 0; d < D_; ++d) {
        // ---------- MoE1 (sparse, gather from fp32 X1) ----------
        zero_k<<<2048, 256, 0, stream>>>((float4*)H1acc, T_*I_/4);
        init_slots_k<<<(NSLOT_+255)/256, 256, 0, stream>>>(stok, sw, cnt);
        gate_k<<<T_, 64, 0, stream>>>(X1, gin_w + (size_t)d*F_*E_, G, F_);
        topk2_k<<<T_/256, 256, 0, stream>>>(G, e2, w2, cnt);
        sched_k<<<1, 64, 0, stream>>>(cnt, pos, s0, s0, 8);
        scatter_k<<<T_/256, 256, 0, stream>>>(e2, w2, pos, stok, sw);
        transp_k<<<dim3(I_/32, F_/32, E_), 256, 0, stream>>>(
            w_in + (size_t)d*E_*F_*I_, Wh, Wl, F_, I_);
        mgemm<A_GATHER, EP_SCATTER, 64, 3><<<dim3(I_/64, GMAX_), 256, 0, stream>>>(
            X1, nullptr, Wh, Wl, H1acc, nullptr, nullptr, I_, F_, s0, stok, sw, nullptr);
        hsplit_k<<<T_*I_/1024, 256, 0, stream>>>(H1acc, Hpadh, Hpadl);

        // ---------- causal conv (dense, pure gl_lds) ----------
        convw_k<<<I_, 256, 0, stream>>>(conv_w + (size_t)d*I_*I_*KW_, Wh, Wl);
        mgemm<A_CONV, EP_RELU_SPLIT, 64, 3><<<dim3(I_/64, T_/128), 256, 0, stream>>>(
            Hpadh, Hpadl, Wh, Wl, HC, HCh, HCl, I_, KW_*I_, nullptr, nullptr, nullptr, nullptr);

        // ---------- MoE2 (sparse, gather from pre-split HC) ----------
        zero_k<<<2048, 256, 0, stream>>>((float4*)O, T_*3*F_/4);
        init_slots_k<<<(NSLOT_+255)/256, 256, 0, stream>>>(stok, sw, cnt);
        gate_k<<<T_, 64, 0, stream>>>(HC, gout_w + (size_t)d*I_*E_, G, I_);
        topk2_k<<<T_/256, 256, 0, stream>>>(G, e2, w2, cnt);
        sched_k<<<1, 64, 0, stream>>>(cnt, pos, s0, s1, 4);
        scatter_k<<<T_/256, 256, 0, stream>>>(e2, w2, pos, stok, sw);
        for (int c = 0; c < 2; ++c) {
            transp_k<<<dim3((3*F_)/32, I_/32, 4), 256, 0, stream>>>(
                w_out + (size_t)d*E_*I_*(3*F_) + (size_t)c*4*I_*(3*F_), Wh, Wl, I_, 3*F_);
            const int4* sc = (c == 0) ? s0 : s1;
            if (d == 0)
                mgemm<A_GATHER2, EP_SCATTER, 128, 3><<<dim3((3*F_)/128, GMAX_), 256, 0, stream>>>(
                    HCh, HCl, Wh, Wl, O, nullptr, nullptr, 3*F_, I_, sc, stok, sw, nullptr);
            else
                mgemm<A_GATHER2, EP_SCATTER, 128, 1><<<dim3((3*F_)/128, GMAX_), 256, 0, stream>>>(
                    HCh, HCl, Wh, Wl, O, nullptr, nullptr, 3*F_, I_, sc, stok, sw, nullptr);
        }

        cum1<<<B_*NCH_, F_, 0, stream>>>(O, CS);
        cum2<<<B_, F_, 0, stream>>>(CS);
        cum3<<<B_*NCH_, F_, 0, stream>>>(O, CS, FP);
        norm_k<<<T_, 256, 0, stream>>>(FP);
        update_k<<<(T_*F_)/256, 256, 0, stream>>>(X0, X1, FP);
    }

    // ---------- final vocab GEMM ----------
    u16* Xch  = (u16*)ar1;
    u16* Xcl  = (u16*)(ar1 + (size_t)T_*(2*F_)*2);
    u16* OWh  = (u16*)ar2;
    u16* OWl  = Hpadh;   // Hpadh+Hpadl adjacent region, 16.8 MB

    concat_k<<<T_, 256, 0, stream>>>(X0, X1, Xch, Xcl);
    outw_k<<<(CLASSES_*2*F_)/1024, 256, 0, stream>>>(out_w, OWh, OWl);
    mgemm<A_SPLIT, EP_FINAL, 128, 3><<<dim3(T_/128, CLASSES_/128), 256, 0, stream>>>(
        OWh, OWl, Xch, Xcl, out, nullptr, nullptr, T_, 2*F_, nullptr, nullptr, nullptr, out_b);
}